// Round 14
// baseline (115.590 us; speedup 1.0000x reference)
//
#include <hip/hip_runtime.h>

typedef __attribute__((ext_vector_type(8))) short bf16x8;
typedef __attribute__((ext_vector_type(4))) float f32x4;
typedef __attribute__((ext_vector_type(2))) unsigned int u32x2;
typedef __attribute__((ext_vector_type(4))) unsigned int u32x4;

__device__ __forceinline__ unsigned short f2bf(float f) {
  return __builtin_bit_cast(unsigned short, (__bf16)f);
}
__device__ __forceinline__ unsigned pk2(float a, float b) {
  return (unsigned)f2bf(a) | ((unsigned)f2bf(b) << 16);
}
__device__ __forceinline__ bf16x8 frag(u32x4 v) { return __builtin_bit_cast(bf16x8, v); }

#if __has_builtin(__builtin_amdgcn_exp2f)
#define EXP2(x) __builtin_amdgcn_exp2f(x)
#else
#define EXP2(x) exp2f(x)
#endif

// wave-level compiler memory fence (cross-lane LDS handoff within a wave)
__device__ __forceinline__ void wfence() {
  asm volatile("" ::: "memory");
  __builtin_amdgcn_wave_barrier();
}
// scheduler fence: pins program order of load-issue groups WITHOUT forcing a
// waitcnt (unlike an asm "v" pin, which requires the value and thus the wait).
__device__ __forceinline__ void sfence() { __builtin_amdgcn_sched_barrier(0); }

#define MFMA16(a, b, c) __builtin_amdgcn_mfma_f32_16x16x32_bf16(a, b, c, 0, 0, 0)

#define LR 72            // 64-col rows, 144 B stride: 16B-aligned, bank-rotating
#define OFF_VT 4608      // K rows at 0; VT rows at 4608; Q (-> attn) rows at 9216
#define OFF_Q  9216
#define ZROW   13824     // 80-ushort zero row for disabled-lane operand reads
#define LDS_TOT 13904    // 27,808 B

// ---- weight prep (identical to R5..R13 -- numerically validated) ----
__global__ void prep_weights(const float* __restrict__ wq, const float* __restrict__ wk,
                             const float* __restrict__ wv, const float* __restrict__ projw,
                             const float* __restrict__ fc1w, const float* __restrict__ fc2w,
                             unsigned short* __restrict__ ws) {
  int c = blockIdx.x, l = threadIdx.x;
  int g = l >> 4, jl = l & 15;
  int kind, T, ks;
  if (c < 8)       { kind = 0; T = c >> 1;        ks = c & 1; }
  else if (c < 16) { kind = 1; T = (c - 8) >> 1;  ks = (c - 8) & 1; }
  else if (c < 24) { kind = 2; T = (c - 16) >> 1; ks = (c - 16) & 1; }
  else if (c < 32) { kind = 3; T = (c - 24) >> 1; ks = (c - 24) & 1; }
  else if (c < 64) { kind = 4; T = (c - 32) >> 1; ks = (c - 32) & 1; }
  else             { kind = 5; T = (c - 64) >> 3; ks = (c - 64) & 7; }
  int n = 16 * T + jl;
  unsigned short* dst = ws + c * 512 + l * 8;
  #pragma unroll
  for (int jj = 0; jj < 8; ++jj) {
    int kp = 16 * (2 * (ks & 1) + (jj >> 2)) + 4 * g + (jj & 3);   // pi slot->col
    int kn = 32 * ks + 8 * g + jj;                                  // natural
    float v;
    if (kind == 0)      v = wq[(n >> 3) * 512 + kp * 8 + (n & 7)] * 0.18033688011f;
    else if (kind == 1) v = wk[(n >> 3) * 512 + kp * 8 + (n & 7)];
    else if (kind == 2) v = wv[(n >> 3) * 512 + kp * 8 + (n & 7)];
    else if (kind == 3) v = projw[kn * 64 + n];
    else if (kind == 4) v = fc1w[kp * 256 + n];
    else                v = fc2w[(64 * (ks >> 1) + kp) * 64 + n];
    dst[jj] = f2bf(v);
  }
}

__device__ __forceinline__ bf16x8 ldw(const unsigned short* __restrict__ wsm,
                                      int chunk, int lane) {
  return *(const bf16x8*)(wsm + chunk * 512 + lane * 8);
}

// fc2 chunk-c fragment chunk indices: (64+8*mi+2*c),(65+8*mi+2*c) for mi=0..3
#define LOAD_F2(dst, c)                                                \
  dst[0] = ldw(wsm, 64 + 2 * (c), lane); dst[1] = ldw(wsm, 65 + 2 * (c), lane); \
  dst[2] = ldw(wsm, 72 + 2 * (c), lane); dst[3] = ldw(wsm, 73 + 2 * (c), lane); \
  dst[4] = ldw(wsm, 80 + 2 * (c), lane); dst[5] = ldw(wsm, 81 + 2 * (c), lane); \
  dst[6] = ldw(wsm, 88 + 2 * (c), lane); dst[7] = ldw(wsm, 89 + 2 * (c), lane);

#define LOAD_F1(dst, c)                                                \
  _Pragma("unroll")                                                    \
  for (int i = 0; i < 8; ++i) dst[i] = ldw(wsm, 32 + 8 * (c) + i, lane);

// consume one FF chunk: fc1 (F1 frags) -> relu -> fc2 (F2 frags) into acc2
#define FF_CHUNK(F1, F2, c)                                            \
  {                                                                    \
    const float* b1c = fc1b + 64 * (c) + 4 * g;                        \
    unsigned fr0, fr1, fr2, fr3, fr4, fr5, fr6, fr7;                   \
    { f32x4 t = MFMA16(F1[0], hc0, zf); t = MFMA16(F1[1], hc1, t);     \
      f32x4 bb = *(const f32x4*)(b1c);                                 \
      fr0 = pk2(fmaxf(t[0] + bb[0], 0.f), fmaxf(t[1] + bb[1], 0.f));   \
      fr1 = pk2(fmaxf(t[2] + bb[2], 0.f), fmaxf(t[3] + bb[3], 0.f)); } \
    { f32x4 t = MFMA16(F1[2], hc0, zf); t = MFMA16(F1[3], hc1, t);     \
      f32x4 bb = *(const f32x4*)(b1c + 16);                            \
      fr2 = pk2(fmaxf(t[0] + bb[0], 0.f), fmaxf(t[1] + bb[1], 0.f));   \
      fr3 = pk2(fmaxf(t[2] + bb[2], 0.f), fmaxf(t[3] + bb[3], 0.f)); } \
    { f32x4 t = MFMA16(F1[4], hc0, zf); t = MFMA16(F1[5], hc1, t);     \
      f32x4 bb = *(const f32x4*)(b1c + 32);                            \
      fr4 = pk2(fmaxf(t[0] + bb[0], 0.f), fmaxf(t[1] + bb[1], 0.f));   \
      fr5 = pk2(fmaxf(t[2] + bb[2], 0.f), fmaxf(t[3] + bb[3], 0.f)); } \
    { f32x4 t = MFMA16(F1[6], hc0, zf); t = MFMA16(F1[7], hc1, t);     \
      f32x4 bb = *(const f32x4*)(b1c + 48);                            \
      fr6 = pk2(fmaxf(t[0] + bb[0], 0.f), fmaxf(t[1] + bb[1], 0.f));   \
      fr7 = pk2(fmaxf(t[2] + bb[2], 0.f), fmaxf(t[3] + bb[3], 0.f)); } \
    bf16x8 bf0 = frag((u32x4){fr0, fr1, fr2, fr3});                    \
    bf16x8 bf1 = frag((u32x4){fr4, fr5, fr6, fr7});                    \
    _Pragma("unroll")                                                  \
    for (int mi = 0; mi < 4; ++mi) {                                   \
      acc2[mi] = MFMA16(F2[2 * mi], bf0, acc2[mi]);                    \
      acc2[mi] = MFMA16(F2[2 * mi + 1], bf1, acc2[mi]);                \
    }                                                                  \
  }

__global__ __launch_bounds__(256, 3) void block_fused(
    const float* __restrict__ x,
    const float* __restrict__ ln1w, const float* __restrict__ ln1b,
    const float* __restrict__ projb,
    const float* __restrict__ ln2w, const float* __restrict__ ln2b,
    const float* __restrict__ fc1b, const float* __restrict__ fc2b,
    const unsigned short* __restrict__ wsm, float* __restrict__ out) {
  __shared__ __attribute__((aligned(16))) unsigned short lds[LDS_TOT];

  const int tid  = threadIdx.x;
  const int w    = tid >> 6;
  const int lane = tid & 63;
  const int g    = lane >> 4;
  const int jl   = lane & 15;
  const size_t b = blockIdx.x;
  const float* xb = x + b * 4096;
  const f32x4 zf = {0.f, 0.f, 0.f, 0.f};

  const int myrow = 16 * w + jl;
  const int krow  = myrow * LR;
  const int qrow  = OFF_Q + myrow * LR;
  const int sigb  = 32 * (w >> 1) + 8 * g + 4 * (w & 1);

  if (tid < 40) ((unsigned*)(lds + ZROW))[tid] = 0u;

  // ---- issue x loads, then QKV weight group A (mt 0,1) -- covered by LN1 ----
  f32x4 xw[4];
  #pragma unroll
  for (int mi = 0; mi < 4; ++mi)
    xw[mi] = *(const f32x4*)(xb + myrow * 64 + 16 * mi + 4 * g);
  bf16x8 A_q00 = ldw(wsm, 0, lane), A_q01 = ldw(wsm, 1, lane);
  bf16x8 A_k00 = ldw(wsm, 8, lane), A_k01 = ldw(wsm, 9, lane);
  bf16x8 A_v00 = ldw(wsm, 16, lane), A_v01 = ldw(wsm, 17, lane);
  bf16x8 A_q10 = ldw(wsm, 2, lane), A_q11 = ldw(wsm, 3, lane);
  bf16x8 A_k10 = ldw(wsm, 10, lane), A_k11 = ldw(wsm, 11, lane);
  bf16x8 A_v10 = ldw(wsm, 18, lane), A_v11 = ldw(wsm, 19, lane);
  sfence();

  // ---------- LN1 ----------
  float mean, rstd;
  unsigned hr[8];
  {
    float s = 0.f, ss = 0.f;
    #pragma unroll
    for (int mi = 0; mi < 4; ++mi)
      #pragma unroll
      for (int r = 0; r < 4; ++r) { s += xw[mi][r]; ss += xw[mi][r] * xw[mi][r]; }
    s  += __shfl_xor(s, 16, 64);  s  += __shfl_xor(s, 32, 64);
    ss += __shfl_xor(ss, 16, 64); ss += __shfl_xor(ss, 32, 64);
    mean = s * 0.015625f;
    rstd = rsqrtf(ss * 0.015625f - mean * mean + 1e-5f);
    #pragma unroll
    for (int mi = 0; mi < 4; ++mi) {
      f32x4 lw = *(const f32x4*)(ln1w + 16 * mi + 4 * g);
      f32x4 lb = *(const f32x4*)(ln1b + 16 * mi + 4 * g);
      float o0 = (xw[mi][0] - mean) * rstd * lw[0] + lb[0];
      float o1 = (xw[mi][1] - mean) * rstd * lw[1] + lb[1];
      float o2 = (xw[mi][2] - mean) * rstd * lw[2] + lb[2];
      float o3 = (xw[mi][3] - mean) * rstd * lw[3] + lb[3];
      hr[2 * mi] = pk2(o0, o1); hr[2 * mi + 1] = pk2(o2, o3);
    }
  }
  bf16x8 hb0 = frag((u32x4){hr[0], hr[1], hr[2], hr[3]});
  bf16x8 hb1 = frag((u32x4){hr[4], hr[5], hr[6], hr[7]});

  // ---- issue QKV weight group B (mt 2,3) -- covered by group-A compute ----
  bf16x8 B_q00 = ldw(wsm, 4, lane), B_q01 = ldw(wsm, 5, lane);
  bf16x8 B_k00 = ldw(wsm, 12, lane), B_k01 = ldw(wsm, 13, lane);
  bf16x8 B_v00 = ldw(wsm, 20, lane), B_v01 = ldw(wsm, 21, lane);
  bf16x8 B_q10 = ldw(wsm, 6, lane), B_q11 = ldw(wsm, 7, lane);
  bf16x8 B_k10 = ldw(wsm, 14, lane), B_k11 = ldw(wsm, 15, lane);
  bf16x8 B_v10 = ldw(wsm, 22, lane), B_v11 = ldw(wsm, 23, lane);
  sfence();

  // ---------- QKV consume (unrolled; group A then group B) ----------
  #define QKV_MT(mt, aq0, aq1, ak0, ak1, bv0, bv1)                              \
  {                                                                             \
    f32x4 q = MFMA16(aq0, hb0, zf); q = MFMA16(aq1, hb1, q);                    \
    *(u32x2*)(lds + qrow + 16 * (mt) + 4 * g) =                                 \
        (u32x2){pk2(q[0], q[1]), pk2(q[2], q[3])};                              \
    f32x4 kk = MFMA16(ak0, hb0, zf); kk = MFMA16(ak1, hb1, kk);                 \
    *(u32x2*)(lds + krow + 16 * (mt) + 4 * g) =                                 \
        (u32x2){pk2(kk[0], kk[1]), pk2(kk[2], kk[3])};                          \
    f32x4 vv = MFMA16(hb0, bv0, zf); vv = MFMA16(hb1, bv1, vv);                 \
    *(u32x2*)(lds + OFF_VT + (16 * (mt) + jl) * LR + sigb) =                    \
        (u32x2){pk2(vv[0], vv[1]), pk2(vv[2], vv[3])};                          \
  }
  QKV_MT(0, A_q00, A_q01, A_k00, A_k01, A_v00, A_v01)
  QKV_MT(1, A_q10, A_q11, A_k10, A_k11, A_v10, A_v11)
  QKV_MT(2, B_q00, B_q01, B_k00, B_k01, B_v00, B_v01)
  QKV_MT(3, B_q10, B_q11, B_k10, B_k11, B_v10, B_v11)

  // ---- issue proj weights (consumed after barrier 2: ~whole-attention cover) ----
  bf16x8 wp[8];
  #pragma unroll
  for (int i = 0; i < 8; ++i) wp[i] = ldw(wsm, 24 + i, lane);
  sfence();
  __syncthreads();   // barrier 1: publish Q, K, VT

  // ---------- attention: wave w owns heads {2w, 2w+1} (R12-validated body) ----------
  {
    const bool g0 = (g == 0), j8 = (jl < 8);
    const int ka0 = g0 ? ((0  + jl) * LR) : ZROW;
    const int ka1 = g0 ? ((16 + jl) * LR) : ZROW;
    const int ka2 = g0 ? ((32 + jl) * LR) : ZROW;
    const int ka3 = g0 ? ((48 + jl) * LR) : ZROW;
    const int qb0 = g0 ? (OFF_Q + (0  + jl) * LR) : ZROW;
    const int qb1 = g0 ? (OFF_Q + (16 + jl) * LR) : ZROW;
    const int qb2 = g0 ? (OFF_Q + (32 + jl) * LR) : ZROW;
    const int qb3 = g0 ? (OFF_Q + (48 + jl) * LR) : ZROW;
    const bool m0 = (4 * g + 0 <= jl), m1 = (4 * g + 1 <= jl);
    const bool m2 = (4 * g + 2 <= jl), m3 = (4 * g + 3 <= jl);
    #pragma clang loop unroll(disable)
    for (int hh = 0; hh < 2; ++hh) {
      const int ho = 16 * w + 8 * hh;
      const int vbase = j8 ? (OFF_VT + (ho + jl) * LR) : ZROW;
      bf16x8 bq0 = *(const bf16x8*)(lds + qb0 + ho);
      bf16x8 bq1 = *(const bf16x8*)(lds + qb1 + ho);
      bf16x8 bq2 = *(const bf16x8*)(lds + qb2 + ho);
      bf16x8 bq3 = *(const bf16x8*)(lds + qb3 + ho);
      bf16x8 k0  = *(const bf16x8*)(lds + ka0 + ho);
      bf16x8 k1  = *(const bf16x8*)(lds + ka1 + ho);
      bf16x8 k2  = *(const bf16x8*)(lds + ka2 + ho);
      bf16x8 k3  = *(const bf16x8*)(lds + ka3 + ho);
      bf16x8 aw0 = *(const bf16x8*)(lds + vbase + 8 * g);
      bf16x8 aw1 = *(const bf16x8*)(lds + vbase + 32 + 8 * g);
      wfence();
      f32x4 s00 = MFMA16(k0, bq0, zf);
      f32x4 s10 = MFMA16(k0, bq1, zf);
      f32x4 s11 = MFMA16(k1, bq1, zf);
      {   // qt 0
        float e0 = m0 ? EXP2(s00[0]) : 0.f, e1 = m1 ? EXP2(s00[1]) : 0.f;
        float e2 = m2 ? EXP2(s00[2]) : 0.f, e3 = m3 ? EXP2(s00[3]) : 0.f;
        float sum = (e0 + e1) + (e2 + e3);
        sum += __shfl_xor(sum, 16, 64); sum += __shfl_xor(sum, 32, 64);
        float inv = __builtin_amdgcn_rcpf(sum);
        bf16x8 bp0 = frag((u32x4){pk2(e0, e1), pk2(e2, e3), 0u, 0u});
        f32x4 pv = MFMA16(aw0, bp0, zf);
        if (g < 2)
          *(u32x2*)(lds + OFF_Q + jl * LR + ho + 4 * g) =
              (u32x2){pk2(pv[0] * inv, pv[1] * inv), pk2(pv[2] * inv, pv[3] * inv)};
      }
      {   // qt 1
        float a0 = EXP2(s10[0]), a1 = EXP2(s10[1]);
        float a2 = EXP2(s10[2]), a3 = EXP2(s10[3]);
        float e0 = m0 ? EXP2(s11[0]) : 0.f, e1 = m1 ? EXP2(s11[1]) : 0.f;
        float e2 = m2 ? EXP2(s11[2]) : 0.f, e3 = m3 ? EXP2(s11[3]) : 0.f;
        float sum = ((a0 + a1) + (a2 + a3)) + ((e0 + e1) + (e2 + e3));
        sum += __shfl_xor(sum, 16, 64); sum += __shfl_xor(sum, 32, 64);
        float inv = __builtin_amdgcn_rcpf(sum);
        bf16x8 bp0 = frag((u32x4){pk2(a0, a1), pk2(a2, a3), pk2(e0, e1), pk2(e2, e3)});
        f32x4 pv = MFMA16(aw0, bp0, zf);
        if (g < 2)
          *(u32x2*)(lds + OFF_Q + (16 + jl) * LR + ho + 4 * g) =
              (u32x2){pk2(pv[0] * inv, pv[1] * inv), pk2(pv[2] * inv, pv[3] * inv)};
      }
      f32x4 s20 = MFMA16(k0, bq2, zf);
      f32x4 s21 = MFMA16(k1, bq2, zf);
      f32x4 s22 = MFMA16(k2, bq2, zf);
      f32x4 s30 = MFMA16(k0, bq3, zf);
      f32x4 s31 = MFMA16(k1, bq3, zf);
      f32x4 s32 = MFMA16(k2, bq3, zf);
      f32x4 s33 = MFMA16(k3, bq3, zf);
      {   // qt 2
        float a0 = EXP2(s20[0]), a1 = EXP2(s20[1]);
        float a2 = EXP2(s20[2]), a3 = EXP2(s20[3]);
        float c0 = EXP2(s21[0]), c1 = EXP2(s21[1]);
        float c2 = EXP2(s21[2]), c3 = EXP2(s21[3]);
        float e0 = m0 ? EXP2(s22[0]) : 0.f, e1 = m1 ? EXP2(s22[1]) : 0.f;
        float e2 = m2 ? EXP2(s22[2]) : 0.f, e3 = m3 ? EXP2(s22[3]) : 0.f;
        float sum = ((a0 + a1) + (a2 + a3)) + ((c0 + c1) + (c2 + c3))
                  + ((e0 + e1) + (e2 + e3));
        sum += __shfl_xor(sum, 16, 64); sum += __shfl_xor(sum, 32, 64);
        float inv = __builtin_amdgcn_rcpf(sum);
        bf16x8 bp0 = frag((u32x4){pk2(a0, a1), pk2(a2, a3), pk2(c0, c1), pk2(c2, c3)});
        bf16x8 bp1 = frag((u32x4){pk2(e0, e1), pk2(e2, e3), 0u, 0u});
        f32x4 pv = MFMA16(aw0, bp0, zf); pv = MFMA16(aw1, bp1, pv);
        if (g < 2)
          *(u32x2*)(lds + OFF_Q + (32 + jl) * LR + ho + 4 * g) =
              (u32x2){pk2(pv[0] * inv, pv[1] * inv), pk2(pv[2] * inv, pv[3] * inv)};
      }
      {   // qt 3
        float a0 = EXP2(s30[0]), a1 = EXP2(s30[1]);
        float a2 = EXP2(s30[2]), a3 = EXP2(s30[3]);
        float c0 = EXP2(s31[0]), c1 = EXP2(s31[1]);
        float c2 = EXP2(s31[2]), c3 = EXP2(s31[3]);
        float d0 = EXP2(s32[0]), d1 = EXP2(s32[1]);
        float d2 = EXP2(s32[2]), d3 = EXP2(s32[3]);
        float e0 = m0 ? EXP2(s33[0]) : 0.f, e1 = m1 ? EXP2(s33[1]) : 0.f;
        float e2 = m2 ? EXP2(s33[2]) : 0.f, e3 = m3 ? EXP2(s33[3]) : 0.f;
        float sum = ((a0 + a1) + (a2 + a3)) + ((c0 + c1) + (c2 + c3))
                  + ((d0 + d1) + (d2 + d3)) + ((e0 + e1) + (e2 + e3));
        sum += __shfl_xor(sum, 16, 64); sum += __shfl_xor(sum, 32, 64);
        float inv = __builtin_amdgcn_rcpf(sum);
        bf16x8 bp0 = frag((u32x4){pk2(a0, a1), pk2(a2, a3), pk2(c0, c1), pk2(c2, c3)});
        bf16x8 bp1 = frag((u32x4){pk2(d0, d1), pk2(d2, d3), pk2(e0, e1), pk2(e2, e3)});
        f32x4 pv = MFMA16(aw0, bp0, zf); pv = MFMA16(aw1, bp1, pv);
        if (g < 2)
          *(u32x2*)(lds + OFF_Q + (48 + jl) * LR + ho + 4 * g) =
              (u32x2){pk2(pv[0] * inv, pv[1] * inv), pk2(pv[2] * inv, pv[3] * inv)};
      }
    }
  }
  __syncthreads();   // barrier 2: publish attn
  bf16x8 bat0 = *(const bf16x8*)(lds + qrow + 8 * g);
  bf16x8 bat1 = *(const bf16x8*)(lds + qrow + 32 + 8 * g);

  // ---------- proj (wp in flight since pre-barrier-1) + residual ----------
  f32x4 x2[4];
  #pragma unroll
  for (int mi = 0; mi < 4; ++mi) {
    f32x4 acc = MFMA16(wp[2 * mi], bat0, zf); acc = MFMA16(wp[2 * mi + 1], bat1, acc);
    f32x4 pb = *(const f32x4*)(projb + 16 * mi + 4 * g);
    x2[mi] = xw[mi] + acc + pb;
  }

  // ---- issue FF chunk-0 fc1+fc2 groups -- covered by LN2 ----
  bf16x8 f1A[8], f2A[8], f1B[8], f2B[8];
  LOAD_F1(f1A, 0)
  LOAD_F2(f2A, 0)
  sfence();

  // ---------- LN2 ----------
  float mean2, rstd2;
  {
    float s = 0.f, ss = 0.f;
    #pragma unroll
    for (int mi = 0; mi < 4; ++mi)
      #pragma unroll
      for (int r = 0; r < 4; ++r) { s += x2[mi][r]; ss += x2[mi][r] * x2[mi][r]; }
    s  += __shfl_xor(s, 16, 64);  s  += __shfl_xor(s, 32, 64);
    ss += __shfl_xor(ss, 16, 64); ss += __shfl_xor(ss, 32, 64);
    mean2 = s * 0.015625f;
    rstd2 = rsqrtf(ss * 0.015625f - mean2 * mean2 + 1e-5f);
  }
  unsigned h2[8];
  #pragma unroll
  for (int mi = 0; mi < 4; ++mi) {
    f32x4 lw = *(const f32x4*)(ln2w + 16 * mi + 4 * g);
    f32x4 lb = *(const f32x4*)(ln2b + 16 * mi + 4 * g);
    float o0 = (x2[mi][0] - mean2) * rstd2 * lw[0] + lb[0];
    float o1 = (x2[mi][1] - mean2) * rstd2 * lw[1] + lb[1];
    float o2 = (x2[mi][2] - mean2) * rstd2 * lw[2] + lb[2];
    float o3 = (x2[mi][3] - mean2) * rstd2 * lw[3] + lb[3];
    h2[2 * mi] = pk2(o0, o1); h2[2 * mi + 1] = pk2(o2, o3);
  }
  bf16x8 hc0 = frag((u32x4){h2[0], h2[1], h2[2], h2[3]});
  bf16x8 hc1 = frag((u32x4){h2[4], h2[5], h2[6], h2[7]});

  // ---------- FF: unrolled, depth-2 double-buffered load pipeline ----------
  f32x4 acc2[4];
  #pragma unroll
  for (int mi = 0; mi < 4; ++mi) acc2[mi] = zf;
  LOAD_F1(f1B, 1) LOAD_F2(f2B, 1) sfence();
  FF_CHUNK(f1A, f2A, 0)
  LOAD_F1(f1A, 2) LOAD_F2(f2A, 2) sfence();
  FF_CHUNK(f1B, f2B, 1)
  LOAD_F1(f1B, 3) LOAD_F2(f2B, 3) sfence();
  FF_CHUNK(f1A, f2A, 2)
  FF_CHUNK(f1B, f2B, 3)

  // ---------- epilogue ----------
  {
    float* ob = out + b * 4096 + myrow * 64;
    #pragma unroll
    for (int mi = 0; mi < 4; ++mi) {
      f32x4 fb = *(const f32x4*)(fc2b + 16 * mi + 4 * g);
      f32x4 o = x2[mi] + acc2[mi] + fb;
      *(f32x4*)(ob + 16 * mi + 4 * g) = o;
    }
  }
}

extern "C" void kernel_launch(void* const* d_in, const int* in_sizes, int n_in,
                              void* d_out, int out_size, void* d_ws, size_t ws_size,
                              hipStream_t stream) {
  const float* x     = (const float*)d_in[0];
  const float* ln1w  = (const float*)d_in[1];
  const float* ln1b  = (const float*)d_in[2];
  const float* wq    = (const float*)d_in[3];
  const float* wk    = (const float*)d_in[4];
  const float* wvp   = (const float*)d_in[5];
  const float* projw = (const float*)d_in[6];
  const float* projb = (const float*)d_in[7];
  const float* ln2w  = (const float*)d_in[8];
  const float* ln2b  = (const float*)d_in[9];
  const float* fc1w  = (const float*)d_in[10];
  const float* fc1b  = (const float*)d_in[11];
  const float* fc2w  = (const float*)d_in[12];
  const float* fc2b  = (const float*)d_in[13];
  unsigned short* ws = (unsigned short*)d_ws;   // 96 KB repacked weights
  float* out = (float*)d_out;

  prep_weights<<<dim3(96), dim3(64), 0, stream>>>(wq, wk, wvp, projw, fc1w, fc2w, ws);

  int nblk = in_sizes[0] / 4096;
  block_fused<<<dim3(nblk), dim3(256), 0, stream>>>(
      x, ln1w, ln1b, projb, ln2w, ln2b, fc1b, fc2b, ws, out);
}

// Round 15
// 100.398 us; speedup vs baseline: 1.1513x; 1.1513x over previous
//
#include <hip/hip_runtime.h>

typedef __attribute__((ext_vector_type(8))) short bf16x8;
typedef __attribute__((ext_vector_type(4))) float f32x4;
typedef __attribute__((ext_vector_type(2))) unsigned int u32x2;
typedef __attribute__((ext_vector_type(4))) unsigned int u32x4;

__device__ __forceinline__ unsigned short f2bf(float f) {
  return __builtin_bit_cast(unsigned short, (__bf16)f);
}
__device__ __forceinline__ unsigned pk2(float a, float b) {
  return (unsigned)f2bf(a) | ((unsigned)f2bf(b) << 16);
}
__device__ __forceinline__ float bf2f(unsigned short h) {
  unsigned u = ((unsigned)h) << 16;
  return __builtin_bit_cast(float, u);
}
__device__ __forceinline__ bf16x8 frag(u32x4 v) { return __builtin_bit_cast(bf16x8, v); }

#if __has_builtin(__builtin_amdgcn_exp2f)
#define EXP2(x) __builtin_amdgcn_exp2f(x)
#else
#define EXP2(x) exp2f(x)
#endif

__device__ __forceinline__ void wfence() {
  asm volatile("" ::: "memory");
  __builtin_amdgcn_wave_barrier();
}

#define MFMA16(a, b, c) __builtin_amdgcn_mfma_f32_16x16x32_bf16(a, b, c, 0, 0, 0)

#define LR 72
#define OFF_VT 4608
#define OFF_Q  9216
#define ZROW   13824
#define LDS_TOT 13904

// ws layout (ushort offsets): [0,49152) weight chunks; h2g at 65536 (128KB);
// x2g at 65536+16777216. Needs ~67.2 MB of d_ws.
#define WS_H2 65536
#define WS_X2 (65536 + 16777216)

// ---- weight prep (identical to R5..R12 -- numerically validated) ----
__global__ void prep_weights(const float* __restrict__ wq, const float* __restrict__ wk,
                             const float* __restrict__ wv, const float* __restrict__ projw,
                             const float* __restrict__ fc1w, const float* __restrict__ fc2w,
                             unsigned short* __restrict__ ws) {
  int c = blockIdx.x, l = threadIdx.x;
  int g = l >> 4, jl = l & 15;
  int kind, T, ks;
  if (c < 8)       { kind = 0; T = c >> 1;        ks = c & 1; }
  else if (c < 16) { kind = 1; T = (c - 8) >> 1;  ks = (c - 8) & 1; }
  else if (c < 24) { kind = 2; T = (c - 16) >> 1; ks = (c - 16) & 1; }
  else if (c < 32) { kind = 3; T = (c - 24) >> 1; ks = (c - 24) & 1; }
  else if (c < 64) { kind = 4; T = (c - 32) >> 1; ks = (c - 32) & 1; }
  else             { kind = 5; T = (c - 64) >> 3; ks = (c - 64) & 7; }
  int n = 16 * T + jl;
  unsigned short* dst = ws + c * 512 + l * 8;
  #pragma unroll
  for (int jj = 0; jj < 8; ++jj) {
    int kp = 16 * (2 * (ks & 1) + (jj >> 2)) + 4 * g + (jj & 3);   // pi slot->col
    int kn = 32 * ks + 8 * g + jj;                                  // natural
    float v;
    if (kind == 0)      v = wq[(n >> 3) * 512 + kp * 8 + (n & 7)] * 0.18033688011f;
    else if (kind == 1) v = wk[(n >> 3) * 512 + kp * 8 + (n & 7)];
    else if (kind == 2) v = wv[(n >> 3) * 512 + kp * 8 + (n & 7)];
    else if (kind == 3) v = projw[kn * 64 + n];
    else if (kind == 4) v = fc1w[kp * 256 + n];
    else                v = fc2w[(64 * (ks >> 1) + kp) * 64 + n];
    dst[jj] = f2bf(v);
  }
}

// ========== K1: LN1 + QKV + attention + proj + residual + LN2 ==========
// R12-validated body; tail stores h2 (pi-packed bf16) and x2 (bf16) to ws.
__global__ __launch_bounds__(256, 4) void block_attn(
    const float* __restrict__ x,
    const float* __restrict__ ln1w, const float* __restrict__ ln1b,
    const float* __restrict__ projb,
    const float* __restrict__ ln2w, const float* __restrict__ ln2b,
    unsigned short* __restrict__ wsm) {
  __shared__ __attribute__((aligned(16))) unsigned short lds[LDS_TOT];

  const int tid  = threadIdx.x;
  const int w    = tid >> 6;
  const int lane = tid & 63;
  const int g    = lane >> 4;
  const int jl   = lane & 15;
  const size_t b = blockIdx.x;
  const float* xb = x + b * 4096;
  const f32x4 zf = {0.f, 0.f, 0.f, 0.f};

  const int myrow = 16 * w + jl;
  const int krow  = myrow * LR;
  const int qrow  = OFF_Q + myrow * LR;
  const int sigb  = 32 * (w >> 1) + 8 * g + 4 * (w & 1);

  if (tid < 40) ((unsigned*)(lds + ZROW))[tid] = 0u;

  // ---------- LN1 fully in registers; xw kept through proj ----------
  f32x4 xw[4];
  float mean, rstd;
  unsigned hr[8];
  {
    float s = 0.f, ss = 0.f;
    #pragma unroll
    for (int mi = 0; mi < 4; ++mi) {
      xw[mi] = *(const f32x4*)(xb + myrow * 64 + 16 * mi + 4 * g);
      #pragma unroll
      for (int r = 0; r < 4; ++r) { s += xw[mi][r]; ss += xw[mi][r] * xw[mi][r]; }
    }
    s  += __shfl_xor(s, 16, 64);  s  += __shfl_xor(s, 32, 64);
    ss += __shfl_xor(ss, 16, 64); ss += __shfl_xor(ss, 32, 64);
    mean = s * 0.015625f;
    rstd = rsqrtf(ss * 0.015625f - mean * mean + 1e-5f);
    #pragma unroll
    for (int mi = 0; mi < 4; ++mi) {
      f32x4 lw = *(const f32x4*)(ln1w + 16 * mi + 4 * g);
      f32x4 lb = *(const f32x4*)(ln1b + 16 * mi + 4 * g);
      float o0 = (xw[mi][0] - mean) * rstd * lw[0] + lb[0];
      float o1 = (xw[mi][1] - mean) * rstd * lw[1] + lb[1];
      float o2 = (xw[mi][2] - mean) * rstd * lw[2] + lb[2];
      float o3 = (xw[mi][3] - mean) * rstd * lw[3] + lb[3];
      hr[2 * mi] = pk2(o0, o1); hr[2 * mi + 1] = pk2(o2, o3);
    }
  }
  bf16x8 hb0 = frag((u32x4){hr[0], hr[1], hr[2], hr[3]});
  bf16x8 hb1 = frag((u32x4){hr[4], hr[5], hr[6], hr[7]});

  // ---------- QKV (rolled) ----------
  #pragma clang loop unroll(disable)
  for (int mt = 0; mt < 4; ++mt) {
    const unsigned short* wq8 = wsm + (2 * mt) * 512 + lane * 8;
    bf16x8 aq0 = *(const bf16x8*)(wq8);
    bf16x8 aq1 = *(const bf16x8*)(wq8 + 512);
    bf16x8 ak0 = *(const bf16x8*)(wq8 + 8 * 512);
    bf16x8 ak1 = *(const bf16x8*)(wq8 + 9 * 512);
    bf16x8 bv0 = *(const bf16x8*)(wq8 + 16 * 512);
    bf16x8 bv1 = *(const bf16x8*)(wq8 + 17 * 512);
    f32x4 q = MFMA16(aq0, hb0, zf); q = MFMA16(aq1, hb1, q);
    *(u32x2*)(lds + qrow + 16 * mt + 4 * g) = (u32x2){pk2(q[0], q[1]), pk2(q[2], q[3])};
    f32x4 kk = MFMA16(ak0, hb0, zf); kk = MFMA16(ak1, hb1, kk);
    *(u32x2*)(lds + krow + 16 * mt + 4 * g) = (u32x2){pk2(kk[0], kk[1]), pk2(kk[2], kk[3])};
    f32x4 vv = MFMA16(hb0, bv0, zf); vv = MFMA16(hb1, bv1, vv);
    *(u32x2*)(lds + OFF_VT + (16 * mt + jl) * LR + sigb) =
        (u32x2){pk2(vv[0], vv[1]), pk2(vv[2], vv[3])};
  }
  __syncthreads();   // barrier 1: publish Q, K, VT

  // ---------- attention: wave w owns heads {2w, 2w+1} ----------
  {
    const bool g0 = (g == 0), j8 = (jl < 8);
    const int ka0 = g0 ? ((0  + jl) * LR) : ZROW;
    const int ka1 = g0 ? ((16 + jl) * LR) : ZROW;
    const int ka2 = g0 ? ((32 + jl) * LR) : ZROW;
    const int ka3 = g0 ? ((48 + jl) * LR) : ZROW;
    const int qb0 = g0 ? (OFF_Q + (0  + jl) * LR) : ZROW;
    const int qb1 = g0 ? (OFF_Q + (16 + jl) * LR) : ZROW;
    const int qb2 = g0 ? (OFF_Q + (32 + jl) * LR) : ZROW;
    const int qb3 = g0 ? (OFF_Q + (48 + jl) * LR) : ZROW;
    const bool m0 = (4 * g + 0 <= jl), m1 = (4 * g + 1 <= jl);
    const bool m2 = (4 * g + 2 <= jl), m3 = (4 * g + 3 <= jl);
    #pragma clang loop unroll(disable)
    for (int hh = 0; hh < 2; ++hh) {
      const int ho = 16 * w + 8 * hh;
      const int vbase = j8 ? (OFF_VT + (ho + jl) * LR) : ZROW;
      bf16x8 bq0 = *(const bf16x8*)(lds + qb0 + ho);
      bf16x8 bq1 = *(const bf16x8*)(lds + qb1 + ho);
      bf16x8 bq2 = *(const bf16x8*)(lds + qb2 + ho);
      bf16x8 bq3 = *(const bf16x8*)(lds + qb3 + ho);
      bf16x8 k0  = *(const bf16x8*)(lds + ka0 + ho);
      bf16x8 k1  = *(const bf16x8*)(lds + ka1 + ho);
      bf16x8 k2  = *(const bf16x8*)(lds + ka2 + ho);
      bf16x8 k3  = *(const bf16x8*)(lds + ka3 + ho);
      bf16x8 aw0 = *(const bf16x8*)(lds + vbase + 8 * g);
      bf16x8 aw1 = *(const bf16x8*)(lds + vbase + 32 + 8 * g);
      wfence();
      f32x4 s00 = MFMA16(k0, bq0, zf);
      f32x4 s10 = MFMA16(k0, bq1, zf);
      f32x4 s11 = MFMA16(k1, bq1, zf);
      {   // qt 0
        float e0 = m0 ? EXP2(s00[0]) : 0.f, e1 = m1 ? EXP2(s00[1]) : 0.f;
        float e2 = m2 ? EXP2(s00[2]) : 0.f, e3 = m3 ? EXP2(s00[3]) : 0.f;
        float sum = (e0 + e1) + (e2 + e3);
        sum += __shfl_xor(sum, 16, 64); sum += __shfl_xor(sum, 32, 64);
        float inv = __builtin_amdgcn_rcpf(sum);
        bf16x8 bp0 = frag((u32x4){pk2(e0, e1), pk2(e2, e3), 0u, 0u});
        f32x4 pv = MFMA16(aw0, bp0, zf);
        if (g < 2)
          *(u32x2*)(lds + OFF_Q + jl * LR + ho + 4 * g) =
              (u32x2){pk2(pv[0] * inv, pv[1] * inv), pk2(pv[2] * inv, pv[3] * inv)};
      }
      {   // qt 1
        float a0 = EXP2(s10[0]), a1 = EXP2(s10[1]);
        float a2 = EXP2(s10[2]), a3 = EXP2(s10[3]);
        float e0 = m0 ? EXP2(s11[0]) : 0.f, e1 = m1 ? EXP2(s11[1]) : 0.f;
        float e2 = m2 ? EXP2(s11[2]) : 0.f, e3 = m3 ? EXP2(s11[3]) : 0.f;
        float sum = ((a0 + a1) + (a2 + a3)) + ((e0 + e1) + (e2 + e3));
        sum += __shfl_xor(sum, 16, 64); sum += __shfl_xor(sum, 32, 64);
        float inv = __builtin_amdgcn_rcpf(sum);
        bf16x8 bp0 = frag((u32x4){pk2(a0, a1), pk2(a2, a3), pk2(e0, e1), pk2(e2, e3)});
        f32x4 pv = MFMA16(aw0, bp0, zf);
        if (g < 2)
          *(u32x2*)(lds + OFF_Q + (16 + jl) * LR + ho + 4 * g) =
              (u32x2){pk2(pv[0] * inv, pv[1] * inv), pk2(pv[2] * inv, pv[3] * inv)};
      }
      f32x4 s20 = MFMA16(k0, bq2, zf);
      f32x4 s21 = MFMA16(k1, bq2, zf);
      f32x4 s22 = MFMA16(k2, bq2, zf);
      f32x4 s30 = MFMA16(k0, bq3, zf);
      f32x4 s31 = MFMA16(k1, bq3, zf);
      f32x4 s32 = MFMA16(k2, bq3, zf);
      f32x4 s33 = MFMA16(k3, bq3, zf);
      {   // qt 2
        float a0 = EXP2(s20[0]), a1 = EXP2(s20[1]);
        float a2 = EXP2(s20[2]), a3 = EXP2(s20[3]);
        float c0 = EXP2(s21[0]), c1 = EXP2(s21[1]);
        float c2 = EXP2(s21[2]), c3 = EXP2(s21[3]);
        float e0 = m0 ? EXP2(s22[0]) : 0.f, e1 = m1 ? EXP2(s22[1]) : 0.f;
        float e2 = m2 ? EXP2(s22[2]) : 0.f, e3 = m3 ? EXP2(s22[3]) : 0.f;
        float sum = ((a0 + a1) + (a2 + a3)) + ((c0 + c1) + (c2 + c3))
                  + ((e0 + e1) + (e2 + e3));
        sum += __shfl_xor(sum, 16, 64); sum += __shfl_xor(sum, 32, 64);
        float inv = __builtin_amdgcn_rcpf(sum);
        bf16x8 bp0 = frag((u32x4){pk2(a0, a1), pk2(a2, a3), pk2(c0, c1), pk2(c2, c3)});
        bf16x8 bp1 = frag((u32x4){pk2(e0, e1), pk2(e2, e3), 0u, 0u});
        f32x4 pv = MFMA16(aw0, bp0, zf); pv = MFMA16(aw1, bp1, pv);
        if (g < 2)
          *(u32x2*)(lds + OFF_Q + (32 + jl) * LR + ho + 4 * g) =
              (u32x2){pk2(pv[0] * inv, pv[1] * inv), pk2(pv[2] * inv, pv[3] * inv)};
      }
      {   // qt 3
        float a0 = EXP2(s30[0]), a1 = EXP2(s30[1]);
        float a2 = EXP2(s30[2]), a3 = EXP2(s30[3]);
        float c0 = EXP2(s31[0]), c1 = EXP2(s31[1]);
        float c2 = EXP2(s31[2]), c3 = EXP2(s31[3]);
        float d0 = EXP2(s32[0]), d1 = EXP2(s32[1]);
        float d2 = EXP2(s32[2]), d3 = EXP2(s32[3]);
        float e0 = m0 ? EXP2(s33[0]) : 0.f, e1 = m1 ? EXP2(s33[1]) : 0.f;
        float e2 = m2 ? EXP2(s33[2]) : 0.f, e3 = m3 ? EXP2(s33[3]) : 0.f;
        float sum = ((a0 + a1) + (a2 + a3)) + ((c0 + c1) + (c2 + c3))
                  + ((d0 + d1) + (d2 + d3)) + ((e0 + e1) + (e2 + e3));
        sum += __shfl_xor(sum, 16, 64); sum += __shfl_xor(sum, 32, 64);
        float inv = __builtin_amdgcn_rcpf(sum);
        bf16x8 bp0 = frag((u32x4){pk2(a0, a1), pk2(a2, a3), pk2(c0, c1), pk2(c2, c3)});
        bf16x8 bp1 = frag((u32x4){pk2(d0, d1), pk2(d2, d3), pk2(e0, e1), pk2(e2, e3)});
        f32x4 pv = MFMA16(aw0, bp0, zf); pv = MFMA16(aw1, bp1, pv);
        if (g < 2)
          *(u32x2*)(lds + OFF_Q + (48 + jl) * LR + ho + 4 * g) =
              (u32x2){pk2(pv[0] * inv, pv[1] * inv), pk2(pv[2] * inv, pv[3] * inv)};
      }
    }
  }
  __syncthreads();   // barrier 2: publish attn
  bf16x8 bat0 = *(const bf16x8*)(lds + qrow + 8 * g);
  bf16x8 bat1 = *(const bf16x8*)(lds + qrow + 32 + 8 * g);

  // ---------- proj + residual ----------
  f32x4 x2[4];
  #pragma unroll
  for (int mi = 0; mi < 4; ++mi) {
    bf16x8 a0 = *(const bf16x8*)(wsm + (24 + 2 * mi) * 512 + lane * 8);
    bf16x8 a1 = *(const bf16x8*)(wsm + (25 + 2 * mi) * 512 + lane * 8);
    f32x4 acc = MFMA16(a0, bat0, zf); acc = MFMA16(a1, bat1, acc);
    f32x4 pb = *(const f32x4*)(projb + 16 * mi + 4 * g);
    x2[mi] = xw[mi] + acc + pb;
  }

  // ---------- LN2 + store h2 (pi-packed) and x2 (bf16) ----------
  float mean2, rstd2;
  {
    float s = 0.f, ss = 0.f;
    #pragma unroll
    for (int mi = 0; mi < 4; ++mi)
      #pragma unroll
      for (int r = 0; r < 4; ++r) { s += x2[mi][r]; ss += x2[mi][r] * x2[mi][r]; }
    s  += __shfl_xor(s, 16, 64);  s  += __shfl_xor(s, 32, 64);
    ss += __shfl_xor(ss, 16, 64); ss += __shfl_xor(ss, 32, 64);
    mean2 = s * 0.015625f;
    rstd2 = rsqrtf(ss * 0.015625f - mean2 * mean2 + 1e-5f);
  }
  unsigned h2[8];
  #pragma unroll
  for (int mi = 0; mi < 4; ++mi) {
    f32x4 lw = *(const f32x4*)(ln2w + 16 * mi + 4 * g);
    f32x4 lb = *(const f32x4*)(ln2b + 16 * mi + 4 * g);
    float o0 = (x2[mi][0] - mean2) * rstd2 * lw[0] + lb[0];
    float o1 = (x2[mi][1] - mean2) * rstd2 * lw[1] + lb[1];
    float o2 = (x2[mi][2] - mean2) * rstd2 * lw[2] + lb[2];
    float o3 = (x2[mi][3] - mean2) * rstd2 * lw[3] + lb[3];
    h2[2 * mi] = pk2(o0, o1); h2[2 * mi + 1] = pk2(o2, o3);
  }
  {
    const size_t t = b * 64 + (size_t)myrow;
    unsigned short* hrow = wsm + WS_H2 + t * 64;
    // ks=0 slots (j=0..7 at this g) = h2[0..3]; ks=1 = h2[4..7]
    *(u32x4*)(hrow + 8 * g)      = (u32x4){h2[0], h2[1], h2[2], h2[3]};
    *(u32x4*)(hrow + 32 + 8 * g) = (u32x4){h2[4], h2[5], h2[6], h2[7]};
    unsigned short* xrow = wsm + WS_X2 + t * 64;
    #pragma unroll
    for (int mi = 0; mi < 4; ++mi)
      *(u32x2*)(xrow + 16 * mi + 4 * g) =
          (u32x2){pk2(x2[mi][0], x2[mi][1]), pk2(x2[mi][2], x2[mi][3])};
  }
}

// ========== K2: FF GEMM (fc1+relu+fc2+residual), barrier-free stream ==========
// Weights LDS-staged once; each block = 128 tokens (2 passes x 64); no
// __syncthreads after the stage barrier; waves fully independent.
__global__ __launch_bounds__(256, 2) void ff_stream(
    const unsigned short* __restrict__ wsm,
    const float* __restrict__ fc1b, const float* __restrict__ fc2b,
    float* __restrict__ out) {
  __shared__ __attribute__((aligned(16))) unsigned short ldsw[32768];  // 64 KB

  const int tid  = threadIdx.x;
  const int w    = tid >> 6;
  const int lane = tid & 63;
  const int g    = lane >> 4;
  const int jl   = lane & 15;
  const int myrow = 16 * w + jl;
  const f32x4 zf = {0.f, 0.f, 0.f, 0.f};

  // stage fc1+fc2 chunks (orig 32..96 -> local 0..64) : 64 KB, coalesced
  {
    const u32x4* src = (const u32x4*)(wsm + 16384);
    u32x4* dst = (u32x4*)ldsw;
    #pragma unroll
    for (int k = 0; k < 16; ++k) dst[k * 256 + tid] = src[k * 256 + tid];
  }
  __syncthreads();

  const unsigned short* h2g = wsm + WS_H2;
  const unsigned short* x2g = wsm + WS_X2;

  #pragma clang loop unroll(disable)
  for (int p = 0; p < 2; ++p) {
    const size_t t = (size_t)blockIdx.x * 128 + p * 64 + myrow;
    const unsigned short* hrow = h2g + t * 64;
    bf16x8 hc0 = *(const bf16x8*)(hrow + 8 * g);
    bf16x8 hc1 = *(const bf16x8*)(hrow + 32 + 8 * g);
    // x2 (bf16) -> f32
    f32x4 x2[4];
    {
      const unsigned short* xrow = x2g + t * 64;
      #pragma unroll
      for (int mi = 0; mi < 4; ++mi) {
        u32x2 v = *(const u32x2*)(xrow + 16 * mi + 4 * g);
        x2[mi][0] = bf2f((unsigned short)(v[0] & 0xFFFF));
        x2[mi][1] = bf2f((unsigned short)(v[0] >> 16));
        x2[mi][2] = bf2f((unsigned short)(v[1] & 0xFFFF));
        x2[mi][3] = bf2f((unsigned short)(v[1] >> 16));
      }
    }
    f32x4 acc2[4];
    #pragma unroll
    for (int mi = 0; mi < 4; ++mi) acc2[mi] = zf;
    #pragma clang loop unroll(disable)
    for (int c = 0; c < 4; ++c) {
      const unsigned short* w1c = ldsw + (8 * c) * 512 + lane * 8;        // fc1 local
      const unsigned short* w2c = ldsw + (32 + 2 * c) * 512 + lane * 8;   // fc2 local
      const float* b1c = fc1b + 64 * c + 4 * g;
      unsigned fr0, fr1, fr2, fr3, fr4, fr5, fr6, fr7;
      {
        bf16x8 a0 = *(const bf16x8*)(w1c);
        bf16x8 a1 = *(const bf16x8*)(w1c + 512);
        f32x4 acc = MFMA16(a0, hc0, zf); acc = MFMA16(a1, hc1, acc);
        f32x4 bb = *(const f32x4*)(b1c);
        fr0 = pk2(fmaxf(acc[0] + bb[0], 0.f), fmaxf(acc[1] + bb[1], 0.f));
        fr1 = pk2(fmaxf(acc[2] + bb[2], 0.f), fmaxf(acc[3] + bb[3], 0.f));
      }
      {
        bf16x8 a0 = *(const bf16x8*)(w1c + 2 * 512);
        bf16x8 a1 = *(const bf16x8*)(w1c + 3 * 512);
        f32x4 acc = MFMA16(a0, hc0, zf); acc = MFMA16(a1, hc1, acc);
        f32x4 bb = *(const f32x4*)(b1c + 16);
        fr2 = pk2(fmaxf(acc[0] + bb[0], 0.f), fmaxf(acc[1] + bb[1], 0.f));
        fr3 = pk2(fmaxf(acc[2] + bb[2], 0.f), fmaxf(acc[3] + bb[3], 0.f));
      }
      {
        bf16x8 a0 = *(const bf16x8*)(w1c + 4 * 512);
        bf16x8 a1 = *(const bf16x8*)(w1c + 5 * 512);
        f32x4 acc = MFMA16(a0, hc0, zf); acc = MFMA16(a1, hc1, acc);
        f32x4 bb = *(const f32x4*)(b1c + 32);
        fr4 = pk2(fmaxf(acc[0] + bb[0], 0.f), fmaxf(acc[1] + bb[1], 0.f));
        fr5 = pk2(fmaxf(acc[2] + bb[2], 0.f), fmaxf(acc[3] + bb[3], 0.f));
      }
      {
        bf16x8 a0 = *(const bf16x8*)(w1c + 6 * 512);
        bf16x8 a1 = *(const bf16x8*)(w1c + 7 * 512);
        f32x4 acc = MFMA16(a0, hc0, zf); acc = MFMA16(a1, hc1, acc);
        f32x4 bb = *(const f32x4*)(b1c + 48);
        fr6 = pk2(fmaxf(acc[0] + bb[0], 0.f), fmaxf(acc[1] + bb[1], 0.f));
        fr7 = pk2(fmaxf(acc[2] + bb[2], 0.f), fmaxf(acc[3] + bb[3], 0.f));
      }
      bf16x8 bf0 = frag((u32x4){fr0, fr1, fr2, fr3});
      bf16x8 bf1 = frag((u32x4){fr4, fr5, fr6, fr7});
      #pragma unroll
      for (int mi = 0; mi < 4; ++mi) {
        bf16x8 w20 = *(const bf16x8*)(w2c + (8 * mi) * 512);
        bf16x8 w21 = *(const bf16x8*)(w2c + (8 * mi + 1) * 512);
        acc2[mi] = MFMA16(w20, bf0, acc2[mi]);
        acc2[mi] = MFMA16(w21, bf1, acc2[mi]);
      }
    }
    // epilogue
    float* ob = out + t * 64;
    #pragma unroll
    for (int mi = 0; mi < 4; ++mi) {
      f32x4 fb = *(const f32x4*)(fc2b + 16 * mi + 4 * g);
      f32x4 o = x2[mi] + acc2[mi] + fb;
      *(f32x4*)(ob + 16 * mi + 4 * g) = o;
    }
  }
}

extern "C" void kernel_launch(void* const* d_in, const int* in_sizes, int n_in,
                              void* d_out, int out_size, void* d_ws, size_t ws_size,
                              hipStream_t stream) {
  const float* x     = (const float*)d_in[0];
  const float* ln1w  = (const float*)d_in[1];
  const float* ln1b  = (const float*)d_in[2];
  const float* wq    = (const float*)d_in[3];
  const float* wk    = (const float*)d_in[4];
  const float* wvp   = (const float*)d_in[5];
  const float* projw = (const float*)d_in[6];
  const float* projb = (const float*)d_in[7];
  const float* ln2w  = (const float*)d_in[8];
  const float* ln2b  = (const float*)d_in[9];
  const float* fc1w  = (const float*)d_in[10];
  const float* fc1b  = (const float*)d_in[11];
  const float* fc2w  = (const float*)d_in[12];
  const float* fc2b  = (const float*)d_in[13];
  unsigned short* ws = (unsigned short*)d_ws;   // needs ~67.2 MB
  float* out = (float*)d_out;

  prep_weights<<<dim3(96), dim3(64), 0, stream>>>(wq, wk, wvp, projw, fc1w, fc2w, ws);

  int nblk = in_sizes[0] / 4096;                 // 4096 elements
  block_attn<<<dim3(nblk), dim3(256), 0, stream>>>(
      x, ln1w, ln1b, projb, ln2w, ln2b, ws);

  int nblk2 = (nblk * 64) / 128;                 // 2048 FF blocks (128 tokens each)
  ff_stream<<<dim3(nblk2), dim3(256), 0, stream>>>(ws, fc1b, fc2b, out);
}